// Round 7
// baseline (532.642 us; speedup 1.0000x reference)
//
#include <hip/hip_runtime.h>
#include <hip/hip_bf16.h>

#define BB   2
#define HH   256
#define WWD  256
#define CC   192
#define WSZ  8
#define TT   64
#define NHD  6
#define DHD  32
#define N3   576

typedef __attribute__((ext_vector_type(8))) short short8;
typedef __attribute__((ext_vector_type(4))) float f32x4;

__device__ inline short bf16_bits(float f) {
  __hip_bfloat16 h = __float2bfloat16(f);
  return __builtin_bit_cast(short, h);
}

// async 1KB stage: whole wave; per-lane 16B global src, linear LDS dst
__device__ inline void stage1k(const short* gsrc, short* ldst, int lane) {
  __builtin_amdgcn_global_load_lds(
      (const __attribute__((address_space(1))) void*)(gsrc + lane * 8),
      (__attribute__((address_space(3))) void*)ldst, 16, 0, 0);
}

// ---- kernel 0: pre-shuffle BOTH weights into bf16 B-frags (one launch) ----
// qkv_w: frags 0..13823 (ncols=576, natural order into wf)
// proj_w: frags 0..4607 (ncols=192, head-major perm into pwf)
__global__ __launch_bounds__(256) void lcam_wshuf2(const float* __restrict__ qkv_w,
                                                   const float* __restrict__ proj_w,
                                                   short* __restrict__ wf,
                                                   short* __restrict__ pwf) {
  int gid = blockIdx.x * 256 + threadIdx.x;
  const float* src; short* dst; int ncols, perm, g;
  if (gid < 13824) { src = qkv_w; dst = wf; ncols = N3; perm = 0; g = gid; }
  else {
    g = gid - 13824;
    if (g >= 4608) return;
    src = proj_w; dst = pwf; ncols = CC; perm = 1;
  }
  int lane = g & 63;
  int s = (g >> 6) % 6;
  int ct = g / 384;
  int col = ct * 16 + (lane & 15);
  int k0 = s * 32 + (lane >> 4) * 8;
  short8 v;
#pragma unroll
  for (int j = 0; j < 8; ++j)
    v[j] = bf16_bits(src[(size_t)(k0 + j) * ncols + col]);
  int didx = perm ? ((s * (ncols / 16) + ct) * 64 + lane) : g;
  *(short8*)(dst + (size_t)didx * 8) = v;
}

// ---------------- kernel 1: spatial sum of x -> sums[b][c] (float4) -------
__global__ __launch_bounds__(192) void lcam_sum_x(const float* __restrict__ x,
                                                  float* __restrict__ sums) {
  int blk = blockIdx.x;            // 1024 blocks: 2 batches * 512 chunks of 128 px
  int b = blk >> 9;
  int chunk = blk & 511;
  const float4* xp = (const float4*)(x + ((size_t)b * 65536 + (size_t)chunk * 128) * CC);
  int t = threadIdx.x;             // 192 = 4 px-groups x 48 float4-channels
  int pg = t / 48, c4 = t % 48;
  float4 acc = {0.f, 0.f, 0.f, 0.f};
  for (int p = 0; p < 32; ++p) {
    float4 v = xp[(size_t)(pg * 32 + p) * 48 + c4];
    acc.x += v.x; acc.y += v.y; acc.z += v.z; acc.w += v.w;
  }
  __shared__ __align__(16) float4 red[192];
  red[t] = acc;
  __syncthreads();
  if (pg == 0) {
    float4 a0 = red[c4], a1 = red[48 + c4], a2 = red[96 + c4], a3 = red[144 + c4];
    float* s = &sums[b * CC + c4 * 4];
    atomicAdd(s + 0, a0.x + a1.x + a2.x + a3.x);
    atomicAdd(s + 1, a0.y + a1.y + a2.y + a3.y);
    atomicAdd(s + 2, a0.z + a1.z + a2.z + a3.z);
    atomicAdd(s + 3, a0.w + a1.w + a2.w + a3.w);
  }
}

// ---------------- kernel 2: global token gt[b][c] ----------------
__global__ void lcam_gt(const float* __restrict__ sums,
                        const float* __restrict__ gt_w,
                        const float* __restrict__ gt_b,
                        float* __restrict__ gt) {
  int b = blockIdx.x;
  int co = threadIdx.x;            // 192 threads
  float acc = gt_b[co];
  const float inv = 1.f / 65536.f;
  for (int c = 0; c < CC; ++c)
    acc += sums[b * CC + c] * inv * gt_w[c * CC + co];
  gt[b * CC + co] = acc;
}

// ---- kernel 3: fused window attention + projection, ping-pong weights ----
// (unchanged from the best-measured R5 variant: 166 us, 49KB LDS)
__global__ __launch_bounds__(256) void lcam_attn(
    const float* __restrict__ x, const float* __restrict__ illu,
    const short* __restrict__ wf, const short* __restrict__ pwf,
    const float* __restrict__ qkv_b, const float* __restrict__ proj_b,
    const float* __restrict__ gt, float* __restrict__ out) {
  __shared__ __align__(16) short wgt[2][6144];  // 2 x 12KB weight slices
  __shared__ __align__(16) short ks[65 * 40];   // k rows, row64 = gt key
  __shared__ __align__(16) short vt[32 * 72];   // v^T [dim][key]
  __shared__ __align__(16) short qs[64 * 40];   // q (wave-private rows); reused as O_h
  __shared__ __align__(16) short ps[64 * 72];   // P unnormalized (wave-private rows)

  int w = blockIdx.x;          // 2048 windows
  int b  = w >> 10;
  int wy = (w >> 5) & 31;
  int wx = w & 31;
  int t  = threadIdx.x;
  int lane = t & 63;
  int rtile = t >> 6;             // wave = 16-row tile
  int m = lane & 15;
  int quad = lane >> 4;
  int key0 = rtile * 16 + quad * 4;   // first C-layout row this lane owns

  size_t base = ((size_t)(b * HH + wy * WSZ) * WWD + wx * WSZ) * CC;

  // ---- prologue: stage Q0 slice into wgt[0] (12 x 1KB, 3 per wave) ----
#pragma unroll
  for (int u = 0; u < 3; ++u) {
    int ii = rtile * 3 + u;
    stage1k(wf + ii * 512, wgt[0] + ii * 512, lane);
  }

  // ---- preload x A-frags (bf16), reused across all heads ----
  int apix = rtile * 16 + m;
  size_t arow = base + (size_t)((apix >> 3) * WWD + (apix & 7)) * CC + quad * 8;
  short8 afrag[6];
#pragma unroll
  for (int s = 0; s < 6; ++s) {
    const float* ap = x + arow + s * 32;
    float4 f0 = *(const float4*)(ap);
    float4 f1 = *(const float4*)(ap + 4);
    short8 v;
    v[0] = bf16_bits(f0.x); v[1] = bf16_bits(f0.y);
    v[2] = bf16_bits(f0.z); v[3] = bf16_bits(f0.w);
    v[4] = bf16_bits(f1.x); v[5] = bf16_bits(f1.y);
    v[6] = bf16_bits(f1.z); v[7] = bf16_bits(f1.w);
    afrag[s] = v;
  }
  const short8* wA8 = (const short8*)wgt[0];
  const short8* wB8 = (const short8*)wgt[1];

  // projection accumulators: 16 rows x 192 cols per wave, summed over heads
  f32x4 pacc[12];
#pragma unroll
  for (int ct = 0; ct < 12; ++ct) {
    f32x4 z = {0.f, 0.f, 0.f, 0.f};
    pacc[ct] = z;
  }

  __syncthreads();   // BAR0: Q0 staged (barrier drains vmcnt)

  for (int h = 0; h < NHD; ++h) {
    // =============== phase Q: compute Q from A; stage K_h -> B ===========
#pragma unroll
    for (int u = 0; u < 3; ++u) {
      int ii = rtile * 3 + u;
      stage1k(wf + (12 + 2 * h) * 3072 + ii * 512, wgt[1] + ii * 512, lane);
    }
    // early loads for this head (hide global latency under MFMA phases)
    float gv0 = gt[b * CC + h * 32 + m];
    float gv1 = gt[b * CC + h * 32 + 16 + m];
    float il0[4], il1[4];
#pragma unroll
    for (int r = 0; r < 4; ++r) {
      int key = key0 + r;
      const float* ip = illu + base + (size_t)((key >> 3) * WWD + (key & 7)) * CC + h * 32;
      il0[r] = ip[m];
      il1[r] = ip[16 + m];
    }
    {
      f32x4 a0 = {0.f,0.f,0.f,0.f}, a1 = {0.f,0.f,0.f,0.f};
      __builtin_amdgcn_s_setprio(1);
#pragma unroll
      for (int s = 0; s < 6; ++s)
        a0 = __builtin_amdgcn_mfma_f32_16x16x32_bf16(afrag[s], wA8[s*64 + lane], a0, 0,0,0);
#pragma unroll
      for (int s = 0; s < 6; ++s)
        a1 = __builtin_amdgcn_mfma_f32_16x16x32_bf16(afrag[s], wA8[384 + s*64 + lane], a1, 0,0,0);
      __builtin_amdgcn_s_setprio(0);
      float b0 = qkv_b[h*32 + m], b1 = qkv_b[h*32 + 16 + m];
#pragma unroll
      for (int r = 0; r < 4; ++r) {
        float v0 = a0[r] + b0, v1 = a1[r] + b1;
        float ss = v0*v0 + v1*v1;
        ss += __shfl_xor(ss, 1); ss += __shfl_xor(ss, 2);
        ss += __shfl_xor(ss, 4); ss += __shfl_xor(ss, 8);
        float scl = 0.17677669529663688f * __builtin_amdgcn_rsqf(fmaxf(ss, 1e-24f));
        int row = key0 + r;
        qs[row*40 + m]      = bf16_bits(v0 * scl);
        qs[row*40 + 16 + m] = bf16_bits(v1 * scl);
      }
    }
    __syncthreads();   // BAR1: K slice staged; A's Q-readers done
    // =============== phase K: compute K from B; stage V_h -> A ===========
#pragma unroll
    for (int u = 0; u < 3; ++u) {
      int ii = rtile * 3 + u;
      stage1k(wf + (24 + 2 * h) * 3072 + ii * 512, wgt[0] + ii * 512, lane);
    }
    {
      f32x4 a0 = {0.f,0.f,0.f,0.f}, a1 = {0.f,0.f,0.f,0.f};
      __builtin_amdgcn_s_setprio(1);
#pragma unroll
      for (int s = 0; s < 6; ++s)
        a0 = __builtin_amdgcn_mfma_f32_16x16x32_bf16(afrag[s], wB8[s*64 + lane], a0, 0,0,0);
#pragma unroll
      for (int s = 0; s < 6; ++s)
        a1 = __builtin_amdgcn_mfma_f32_16x16x32_bf16(afrag[s], wB8[384 + s*64 + lane], a1, 0,0,0);
      __builtin_amdgcn_s_setprio(0);
      float b0 = qkv_b[192 + h*32 + m], b1 = qkv_b[192 + h*32 + 16 + m];
#pragma unroll
      for (int r = 0; r < 4; ++r) {
        float v0 = a0[r] + b0, v1 = a1[r] + b1;
        float ss = v0*v0 + v1*v1;
        ss += __shfl_xor(ss, 1); ss += __shfl_xor(ss, 2);
        ss += __shfl_xor(ss, 4); ss += __shfl_xor(ss, 8);
        float scl = __builtin_amdgcn_rsqf(fmaxf(ss, 1e-24f));
        int row = key0 + r;
        ks[row*40 + m]      = bf16_bits(v0 * scl);
        ks[row*40 + 16 + m] = bf16_bits(v1 * scl);
      }
    }
    __syncthreads();   // BAR2: V slice staged; B's K-readers done
    // =============== phase V: compute V from A; stage proj_h -> B ========
#pragma unroll
    for (int u = 0; u < 3; ++u) {
      int ii = rtile * 3 + u;
      stage1k(pwf + h * 6144 + ii * 512, wgt[1] + ii * 512, lane);
    }
    {
      f32x4 a0 = {0.f,0.f,0.f,0.f}, a1 = {0.f,0.f,0.f,0.f};
      __builtin_amdgcn_s_setprio(1);
#pragma unroll
      for (int s = 0; s < 6; ++s)
        a0 = __builtin_amdgcn_mfma_f32_16x16x32_bf16(afrag[s], wA8[s*64 + lane], a0, 0,0,0);
#pragma unroll
      for (int s = 0; s < 6; ++s)
        a1 = __builtin_amdgcn_mfma_f32_16x16x32_bf16(afrag[s], wA8[384 + s*64 + lane], a1, 0,0,0);
      __builtin_amdgcn_s_setprio(0);
      float b0 = qkv_b[384 + h*32 + m], b1 = qkv_b[384 + h*32 + 16 + m];
#pragma unroll
      for (int r = 0; r < 4; ++r) {
        int key = key0 + r;
        float s0 = __builtin_amdgcn_rcpf(1.f + __expf(-il0[r]));
        float s1 = __builtin_amdgcn_rcpf(1.f + __expf(-il1[r]));
        vt[m*72 + key]        = bf16_bits((a0[r] + b0) * (1.f + s0));
        vt[(16 + m)*72 + key] = bf16_bits((a1[r] + b1) * (1.f + s1));
      }
    }
    // global token = 65th key (raw gt, not normed/modulated)
    if (t < DHD) ks[64*40 + t] = bf16_bits(gt[b*CC + h*DHD + t]);
    __syncthreads();   // BAR3: proj slice staged; ks/vt/gt-key visible
    // ========== phase attn: QK/softmax/PV/proj; stage Q_{h+1} -> A =======
    if (h < NHD - 1) {
#pragma unroll
      for (int u = 0; u < 3; ++u) {
        int ii = rtile * 3 + u;
        stage1k(wf + 2 * (h + 1) * 3072 + ii * 512, wgt[0] + ii * 512, lane);
      }
    }
    short8 qa = *(const short8*)(qs + (rtile*16 + m)*40 + quad*8);
    f32x4 sc[5];
#pragma unroll
    for (int ct = 0; ct < 4; ++ct) {
      short8 kb = *(const short8*)(ks + (ct*16 + m)*40 + quad*8);
      f32x4 z = {0.f,0.f,0.f,0.f};
      sc[ct] = __builtin_amdgcn_mfma_f32_16x16x32_bf16(qa, kb, z, 0,0,0);
    }
    {
      short8 kb = *(const short8*)(ks + 64*40 + quad*8);  // all lanes: gt row (bcast)
      f32x4 z = {0.f,0.f,0.f,0.f};
      sc[4] = __builtin_amdgcn_mfma_f32_16x16x32_bf16(qa, kb, z, 0,0,0);
    }
    // ---- softmax: scores bounded (|s|<=0.177), no max-sub; denom deferred
    float p64v[4], invr[4];
#pragma unroll
    for (int r = 0; r < 4; ++r) {
      float e0 = __expf(sc[0][r]), e1 = __expf(sc[1][r]);
      float e2 = __expf(sc[2][r]), e3 = __expf(sc[3][r]);
      float e4 = (m == 0) ? __expf(sc[4][r]) : 0.f;   // gt key valid once per row
      int row = key0 + r;
      ps[row*72 + m]      = bf16_bits(e0);
      ps[row*72 + 16 + m] = bf16_bits(e1);
      ps[row*72 + 32 + m] = bf16_bits(e2);
      ps[row*72 + 48 + m] = bf16_bits(e3);
      float sum = e0 + e1 + e2 + e3 + e4;
      sum += __shfl_xor(sum, 1); sum += __shfl_xor(sum, 2);
      sum += __shfl_xor(sum, 4); sum += __shfl_xor(sum, 8);
      invr[r] = __builtin_amdgcn_rcpf(sum);
      p64v[r] = e4;
    }
    // ---- PV (keys 0..63) + rank-1 gt update, normalize at O ----
    f32x4 o0 = {0.f,0.f,0.f,0.f}, o1 = {0.f,0.f,0.f,0.f};
    __builtin_amdgcn_s_setprio(1);
#pragma unroll
    for (int kc = 0; kc < 2; ++kc) {
      short8 pa  = *(const short8*)(ps + (rtile*16 + m)*72 + kc*32 + quad*8);
      short8 vb0 = *(const short8*)(vt + m*72        + kc*32 + quad*8);
      short8 vb1 = *(const short8*)(vt + (16 + m)*72 + kc*32 + quad*8);
      o0 = __builtin_amdgcn_mfma_f32_16x16x32_bf16(pa, vb0, o0, 0,0,0);
      o1 = __builtin_amdgcn_mfma_f32_16x16x32_bf16(pa, vb1, o1, 0,0,0);
    }
    __builtin_amdgcn_s_setprio(0);
    // O_h staged into qs (wave-private rows; qa reads are done above)
#pragma unroll
    for (int r = 0; r < 4; ++r) {
      float pr = __shfl(p64v[r], lane & 48);   // e4 from lane m==0 of quad
      int row = key0 + r;
      qs[row*40 + m]      = bf16_bits((o0[r] + pr * gv0) * invr[r]);
      qs[row*40 + 16 + m] = bf16_bits((o1[r] + pr * gv1) * invr[r]);
    }
    // ---- accumulate this head's projection slice from B ----
    short8 oa = *(const short8*)(qs + (rtile*16 + m)*40 + quad*8);
    __builtin_amdgcn_s_setprio(1);
#pragma unroll
    for (int ct = 0; ct < 12; ++ct)
      pacc[ct] = __builtin_amdgcn_mfma_f32_16x16x32_bf16(oa, wB8[ct*64 + lane], pacc[ct], 0,0,0);
    __builtin_amdgcn_s_setprio(0);
    __syncthreads();   // BAR4: attn reads done; Q_{h+1} staged
  }
  // ---- epilogue: bias + coalesced store ----
#pragma unroll
  for (int ct = 0; ct < 12; ++ct) {
    float bias = proj_b[ct*16 + m];
#pragma unroll
    for (int r = 0; r < 4; ++r) {
      int row = key0 + r;
      out[base + (size_t)((row >> 3) * WWD + (row & 7)) * CC + ct*16 + m] = pacc[ct][r] + bias;
    }
  }
}

// ------ kernel 5: dwconv -> gelu -> dwconv, += into out (float4-channel) ---
__global__ __launch_bounds__(256) void lcam_pos(const float* __restrict__ x,
                                                const float* __restrict__ w1,
                                                const float* __restrict__ w2,
                                                float* __restrict__ out) {
  __shared__ __align__(16) float xt[20 * 20 * 16];
  __shared__ __align__(16) float t1[18 * 18 * 16];
  __shared__ float wl1[16 * 9], wl2[16 * 9];
  int blk = blockIdx.x;             // b(2) * ty(16) * tx(16) * cg(12)
  int cgI = blk % 12; int tmp = blk / 12;
  int tx = tmp % 16; tmp /= 16;
  int ty = tmp % 16; int b = tmp / 16;
  int c0 = cgI * 16;
  int y0 = ty * 16, x0 = tx * 16;
  int t = threadIdx.x;
  int cc4 = t & 3;                  // invariant float4-channel slot (stride 256 = 0 mod 4)
  if (t < 144) { wl1[t] = w1[c0 * 9 + t]; wl2[t] = w2[c0 * 9 + t]; }
  // stage x halo 20x20x16 (zero outside image = SAME zero pad)
  for (int vi = t; vi < 1600; vi += 256) {
    int q4 = vi & 3;
    int lin = vi >> 2;
    int xx = lin % 20, yy = lin / 20;
    int gy = y0 - 2 + yy, gx = x0 - 2 + xx;
    float4 v = {0.f, 0.f, 0.f, 0.f};
    if (gy >= 0 && gy < HH && gx >= 0 && gx < WWD)
      v = *(const float4*)(x + (((size_t)b * HH + gy) * WWD + gx) * CC + c0 + q4 * 4);
    *(float4*)(xt + (yy * 20 + xx) * 16 + q4 * 4) = v;
  }
  __syncthreads();
  // hoist this thread's 4-channel weight taps into registers
  float w1r[4][9], w2r[4][9];
#pragma unroll
  for (int j = 0; j < 4; ++j)
#pragma unroll
    for (int k = 0; k < 9; ++k) {
      w1r[j][k] = wl1[(cc4 * 4 + j) * 9 + k];
      w2r[j][k] = wl2[(cc4 * 4 + j) * 9 + k];
    }
  // conv1 + exact gelu -> t1 halo 18x18x16 (float4); 0 outside image
  for (int idx = t; idx < 1296; idx += 256) {
    int lin = idx >> 2;
    int xx = lin % 18, yy = lin / 18;
    int gy = y0 - 1 + yy, gx = x0 - 1 + xx;
    float4 r = {0.f, 0.f, 0.f, 0.f};
    if (gy >= 0 && gy < HH && gx >= 0 && gx < WWD) {
#pragma unroll
      for (int ky = 0; ky < 3; ++ky)
#pragma unroll
        for (int kx = 0; kx < 3; ++kx) {
          float4 v = *(const float4*)(xt + ((yy + ky) * 20 + xx + kx) * 16 + cc4 * 4);
          int k = ky * 3 + kx;
          r.x += v.x * w1r[0][k];
          r.y += v.y * w1r[1][k];
          r.z += v.z * w1r[2][k];
          r.w += v.w * w1r[3][k];
        }
      r.x = 0.5f * r.x * (1.f + erff(r.x * 0.70710678118654752f));
      r.y = 0.5f * r.y * (1.f + erff(r.y * 0.70710678118654752f));
      r.z = 0.5f * r.z * (1.f + erff(r.z * 0.70710678118654752f));
      r.w = 0.5f * r.w * (1.f + erff(r.w * 0.70710678118654752f));
    }
    *(float4*)(t1 + (yy * 18 + xx) * 16 + cc4 * 4) = r;
  }
  __syncthreads();
  // conv2 + add into out (float4 RMW, coalesced dwordx4)
  for (int idx = t; idx < 1024; idx += 256) {
    int lin = idx >> 2;
    int xx = lin & 15, yy = lin >> 4;
    float4 r = {0.f, 0.f, 0.f, 0.f};
#pragma unroll
    for (int ky = 0; ky < 3; ++ky)
#pragma unroll
      for (int kx = 0; kx < 3; ++kx) {
        float4 v = *(const float4*)(t1 + ((yy + ky) * 18 + xx + kx) * 16 + cc4 * 4);
        int k = ky * 3 + kx;
        r.x += v.x * w2r[0][k];
        r.y += v.y * w2r[1][k];
        r.z += v.z * w2r[2][k];
        r.w += v.w * w2r[3][k];
      }
    size_t o = (((size_t)b * HH + y0 + yy) * WWD + x0 + xx) * CC + c0 + cc4 * 4;
    float4 cur = *(float4*)(out + o);
    cur.x += r.x; cur.y += r.y; cur.z += r.z; cur.w += r.w;
    *(float4*)(out + o) = cur;
  }
}

extern "C" void kernel_launch(void* const* d_in, const int* in_sizes, int n_in,
                              void* d_out, int out_size, void* d_ws, size_t ws_size,
                              hipStream_t stream) {
  const float* x       = (const float*)d_in[0];
  const float* illu    = (const float*)d_in[1];
  const float* gt_w    = (const float*)d_in[2];
  const float* gt_b    = (const float*)d_in[3];
  const float* qkv_w   = (const float*)d_in[4];
  const float* qkv_b   = (const float*)d_in[5];
  const float* proj_w  = (const float*)d_in[6];
  const float* proj_b  = (const float*)d_in[7];
  const float* conv1_w = (const float*)d_in[8];
  const float* conv2_w = (const float*)d_in[9];
  float* out = (float*)d_out;

  short* wf   = (short*)d_ws;                          // 36*6*64*8 bf16 = 221184 B
  short* pwf  = (short*)((char*)d_ws + 221184);        // 12*6*64*8 bf16 =  73728 B (head-major)
  float* sums = (float*)((char*)d_ws + 221184 + 73728);
  float* gt   = sums + BB * CC;

  hipMemsetAsync(sums, 0, BB * CC * sizeof(float), stream);
  lcam_wshuf2<<<72, 256, 0, stream>>>(qkv_w, proj_w, wf, pwf);
  lcam_sum_x<<<1024, 192, 0, stream>>>(x, sums);
  lcam_gt<<<BB, CC, 0, stream>>>(sums, gt_w, gt_b, gt);
  lcam_attn<<<2048, 256, 0, stream>>>(x, illu, wf, pwf, qkv_b, proj_b, gt, out);
  lcam_pos<<<6144, 256, 0, stream>>>(x, conv1_w, conv2_w, out);
}

// Round 8
// 523.034 us; speedup vs baseline: 1.0184x; 1.0184x over previous
//
#include <hip/hip_runtime.h>
#include <hip/hip_bf16.h>

#define BB   2
#define HH   256
#define WWD  256
#define CC   192
#define WSZ  8
#define TT   64
#define NHD  6
#define DHD  32
#define N3   576

typedef __attribute__((ext_vector_type(8))) short short8;
typedef __attribute__((ext_vector_type(4))) float f32x4;

__device__ inline short bf16_bits(float f) {
  __hip_bfloat16 h = __float2bfloat16(f);
  return __builtin_bit_cast(short, h);
}

// sum over the 16 m-lanes of each 16-lane row, result in ALL lanes.
// DPP (VALU pipe) instead of ds_bpermute shfl chains (LDS pipe).
__device__ inline float row_sum16(float v) {
  int x;
  x = __builtin_amdgcn_update_dpp(0, __builtin_bit_cast(int, v), 0xB1, 0xf, 0xf, true);  // quad_perm xor1
  v += __builtin_bit_cast(float, x);
  x = __builtin_amdgcn_update_dpp(0, __builtin_bit_cast(int, v), 0x4E, 0xf, 0xf, true);  // quad_perm xor2
  v += __builtin_bit_cast(float, x);
  x = __builtin_amdgcn_update_dpp(0, __builtin_bit_cast(int, v), 0x124, 0xf, 0xf, true); // row_ror:4
  v += __builtin_bit_cast(float, x);
  x = __builtin_amdgcn_update_dpp(0, __builtin_bit_cast(int, v), 0x128, 0xf, 0xf, true); // row_ror:8
  v += __builtin_bit_cast(float, x);
  return v;
}

// async 1KB stage: whole wave; per-lane 16B global src, linear LDS dst
__device__ inline void stage1k(const short* gsrc, short* ldst, int lane) {
  __builtin_amdgcn_global_load_lds(
      (const __attribute__((address_space(1))) void*)(gsrc + lane * 8),
      (__attribute__((address_space(3))) void*)ldst, 16, 0, 0);
}

// ---- kernel 0: pre-shuffle BOTH weights into bf16 B-frags (one launch) ----
__global__ __launch_bounds__(256) void lcam_wshuf2(const float* __restrict__ qkv_w,
                                                   const float* __restrict__ proj_w,
                                                   short* __restrict__ wf,
                                                   short* __restrict__ pwf) {
  int gid = blockIdx.x * 256 + threadIdx.x;
  const float* src; short* dst; int ncols, perm, g;
  if (gid < 13824) { src = qkv_w; dst = wf; ncols = N3; perm = 0; g = gid; }
  else {
    g = gid - 13824;
    if (g >= 4608) return;
    src = proj_w; dst = pwf; ncols = CC; perm = 1;
  }
  int lane = g & 63;
  int s = (g >> 6) % 6;
  int ct = g / 384;
  int col = ct * 16 + (lane & 15);
  int k0 = s * 32 + (lane >> 4) * 8;
  short8 v;
#pragma unroll
  for (int j = 0; j < 8; ++j)
    v[j] = bf16_bits(src[(size_t)(k0 + j) * ncols + col]);
  int didx = perm ? ((s * (ncols / 16) + ct) * 64 + lane) : g;
  *(short8*)(dst + (size_t)didx * 8) = v;
}

// ---------------- kernel 1: spatial sum of x -> sums[b][c] (float4) -------
__global__ __launch_bounds__(192) void lcam_sum_x(const float* __restrict__ x,
                                                  float* __restrict__ sums) {
  int blk = blockIdx.x;            // 1024 blocks: 2 batches * 512 chunks of 128 px
  int b = blk >> 9;
  int chunk = blk & 511;
  const float4* xp = (const float4*)(x + ((size_t)b * 65536 + (size_t)chunk * 128) * CC);
  int t = threadIdx.x;             // 192 = 4 px-groups x 48 float4-channels
  int pg = t / 48, c4 = t % 48;
  float4 acc = {0.f, 0.f, 0.f, 0.f};
  for (int p = 0; p < 32; ++p) {
    float4 v = xp[(size_t)(pg * 32 + p) * 48 + c4];
    acc.x += v.x; acc.y += v.y; acc.z += v.z; acc.w += v.w;
  }
  __shared__ __align__(16) float4 red[192];
  red[t] = acc;
  __syncthreads();
  if (pg == 0) {
    float4 a0 = red[c4], a1 = red[48 + c4], a2 = red[96 + c4], a3 = red[144 + c4];
    float* s = &sums[b * CC + c4 * 4];
    atomicAdd(s + 0, a0.x + a1.x + a2.x + a3.x);
    atomicAdd(s + 1, a0.y + a1.y + a2.y + a3.y);
    atomicAdd(s + 2, a0.z + a1.z + a2.z + a3.z);
    atomicAdd(s + 3, a0.w + a1.w + a2.w + a3.w);
  }
}

// ---------------- kernel 2: global token gt[b][c] ----------------
__global__ void lcam_gt(const float* __restrict__ sums,
                        const float* __restrict__ gt_w,
                        const float* __restrict__ gt_b,
                        float* __restrict__ gt) {
  int b = blockIdx.x;
  int co = threadIdx.x;            // 192 threads
  float acc = gt_b[co];
  const float inv = 1.f / 65536.f;
  for (int c = 0; c < CC; ++c)
    acc += sums[b * CC + c] * inv * gt_w[c * CC + co];
  gt[b * CC + co] = acc;
}

// ---- kernel 3: fused window attention + projection, ping-pong weights ----
// R5 structure + (a) ALL illu values prologue-loaded into registers (kills
// the per-head HBM-latency stall exposed at each barrier's vmcnt drain),
// (b) DPP row-reduces instead of shfl chains (VALU pipe, not LDS pipe),
// (c) e4/gt-score uniformity exploited (no lane mask / no broadcast shfl).
__global__ __launch_bounds__(256) void lcam_attn(
    const float* __restrict__ x, const float* __restrict__ illu,
    const short* __restrict__ wf, const short* __restrict__ pwf,
    const float* __restrict__ qkv_b, const float* __restrict__ proj_b,
    const float* __restrict__ gt, float* __restrict__ out) {
  __shared__ __align__(16) short wgt[2][6144];  // 2 x 12KB weight slices
  __shared__ __align__(16) short ks[65 * 40];   // k rows, row64 = gt key
  __shared__ __align__(16) short vt[32 * 72];   // v^T [dim][key]
  __shared__ __align__(16) short qs[64 * 40];   // q (wave-private rows); reused as O_h
  __shared__ __align__(16) short ps[64 * 72];   // P unnormalized (wave-private rows)

  int w = blockIdx.x;          // 2048 windows
  int b  = w >> 10;
  int wy = (w >> 5) & 31;
  int wx = w & 31;
  int t  = threadIdx.x;
  int lane = t & 63;
  int rtile = t >> 6;             // wave = 16-row tile
  int m = lane & 15;
  int quad = lane >> 4;
  int key0 = rtile * 16 + quad * 4;   // first C-layout row this lane owns

  size_t base = ((size_t)(b * HH + wy * WSZ) * WWD + wx * WSZ) * CC;

  // ---- prologue: stage Q0 slice into wgt[0] (12 x 1KB, 3 per wave) ----
#pragma unroll
  for (int u = 0; u < 3; ++u) {
    int ii = rtile * 3 + u;
    stage1k(wf + ii * 512, wgt[0] + ii * 512, lane);
  }

  // ---- preload x A-frags (bf16), reused across all heads ----
  int apix = rtile * 16 + m;
  size_t arow = base + (size_t)((apix >> 3) * WWD + (apix & 7)) * CC + quad * 8;
  short8 afrag[6];
#pragma unroll
  for (int s = 0; s < 6; ++s) {
    const float* ap = x + arow + s * 32;
    float4 f0 = *(const float4*)(ap);
    float4 f1 = *(const float4*)(ap + 4);
    short8 v;
    v[0] = bf16_bits(f0.x); v[1] = bf16_bits(f0.y);
    v[2] = bf16_bits(f0.z); v[3] = bf16_bits(f0.w);
    v[4] = bf16_bits(f1.x); v[5] = bf16_bits(f1.y);
    v[6] = bf16_bits(f1.z); v[7] = bf16_bits(f1.w);
    afrag[s] = v;
  }

  // ---- prologue: ALL illu values for all heads -> 48 VGPRs ----
  float ila[NHD][4], ilb[NHD][4];
#pragma unroll
  for (int r = 0; r < 4; ++r) {
    int key = key0 + r;
    const float* ip = illu + base + (size_t)((key >> 3) * WWD + (key & 7)) * CC;
#pragma unroll
    for (int h = 0; h < NHD; ++h) {
      ila[h][r] = ip[h * 32 + m];
      ilb[h][r] = ip[h * 32 + 16 + m];
    }
  }

  const short8* wA8 = (const short8*)wgt[0];
  const short8* wB8 = (const short8*)wgt[1];

  // projection accumulators: 16 rows x 192 cols per wave, summed over heads
  f32x4 pacc[12];
#pragma unroll
  for (int ct = 0; ct < 12; ++ct) {
    f32x4 z = {0.f, 0.f, 0.f, 0.f};
    pacc[ct] = z;
  }

  __syncthreads();   // BAR0: Q0 staged; prologue loads drained once

#pragma unroll
  for (int h = 0; h < NHD; ++h) {
    // =============== phase Q: compute Q from A; stage K_h -> B ===========
#pragma unroll
    for (int u = 0; u < 3; ++u) {
      int ii = rtile * 3 + u;
      stage1k(wf + (12 + 2 * h) * 3072 + ii * 512, wgt[1] + ii * 512, lane);
    }
    float gv0 = gt[b * CC + h * 32 + m];
    float gv1 = gt[b * CC + h * 32 + 16 + m];
    {
      f32x4 a0 = {0.f,0.f,0.f,0.f}, a1 = {0.f,0.f,0.f,0.f};
      __builtin_amdgcn_s_setprio(1);
#pragma unroll
      for (int s = 0; s < 6; ++s)
        a0 = __builtin_amdgcn_mfma_f32_16x16x32_bf16(afrag[s], wA8[s*64 + lane], a0, 0,0,0);
#pragma unroll
      for (int s = 0; s < 6; ++s)
        a1 = __builtin_amdgcn_mfma_f32_16x16x32_bf16(afrag[s], wA8[384 + s*64 + lane], a1, 0,0,0);
      __builtin_amdgcn_s_setprio(0);
      float b0 = qkv_b[h*32 + m], b1 = qkv_b[h*32 + 16 + m];
#pragma unroll
      for (int r = 0; r < 4; ++r) {
        float v0 = a0[r] + b0, v1 = a1[r] + b1;
        float ss = row_sum16(v0*v0 + v1*v1);
        float scl = 0.17677669529663688f * __builtin_amdgcn_rsqf(fmaxf(ss, 1e-24f));
        int row = key0 + r;
        qs[row*40 + m]      = bf16_bits(v0 * scl);
        qs[row*40 + 16 + m] = bf16_bits(v1 * scl);
      }
    }
    __syncthreads();   // BAR1: K slice staged; A's Q-readers done
    // =============== phase K: compute K from B; stage V_h -> A ===========
#pragma unroll
    for (int u = 0; u < 3; ++u) {
      int ii = rtile * 3 + u;
      stage1k(wf + (24 + 2 * h) * 3072 + ii * 512, wgt[0] + ii * 512, lane);
    }
    {
      f32x4 a0 = {0.f,0.f,0.f,0.f}, a1 = {0.f,0.f,0.f,0.f};
      __builtin_amdgcn_s_setprio(1);
#pragma unroll
      for (int s = 0; s < 6; ++s)
        a0 = __builtin_amdgcn_mfma_f32_16x16x32_bf16(afrag[s], wB8[s*64 + lane], a0, 0,0,0);
#pragma unroll
      for (int s = 0; s < 6; ++s)
        a1 = __builtin_amdgcn_mfma_f32_16x16x32_bf16(afrag[s], wB8[384 + s*64 + lane], a1, 0,0,0);
      __builtin_amdgcn_s_setprio(0);
      float b0 = qkv_b[192 + h*32 + m], b1 = qkv_b[192 + h*32 + 16 + m];
#pragma unroll
      for (int r = 0; r < 4; ++r) {
        float v0 = a0[r] + b0, v1 = a1[r] + b1;
        float ss = row_sum16(v0*v0 + v1*v1);
        float scl = __builtin_amdgcn_rsqf(fmaxf(ss, 1e-24f));
        int row = key0 + r;
        ks[row*40 + m]      = bf16_bits(v0 * scl);
        ks[row*40 + 16 + m] = bf16_bits(v1 * scl);
      }
    }
    __syncthreads();   // BAR2: V slice staged; B's K-readers done
    // =============== phase V: compute V from A; stage proj_h -> B ========
#pragma unroll
    for (int u = 0; u < 3; ++u) {
      int ii = rtile * 3 + u;
      stage1k(pwf + h * 6144 + ii * 512, wgt[1] + ii * 512, lane);
    }
    {
      f32x4 a0 = {0.f,0.f,0.f,0.f}, a1 = {0.f,0.f,0.f,0.f};
      __builtin_amdgcn_s_setprio(1);
#pragma unroll
      for (int s = 0; s < 6; ++s)
        a0 = __builtin_amdgcn_mfma_f32_16x16x32_bf16(afrag[s], wA8[s*64 + lane], a0, 0,0,0);
#pragma unroll
      for (int s = 0; s < 6; ++s)
        a1 = __builtin_amdgcn_mfma_f32_16x16x32_bf16(afrag[s], wA8[384 + s*64 + lane], a1, 0,0,0);
      __builtin_amdgcn_s_setprio(0);
      float b0 = qkv_b[384 + h*32 + m], b1 = qkv_b[384 + h*32 + 16 + m];
#pragma unroll
      for (int r = 0; r < 4; ++r) {
        int key = key0 + r;
        float s0 = __builtin_amdgcn_rcpf(1.f + __expf(-ila[h][r]));
        float s1 = __builtin_amdgcn_rcpf(1.f + __expf(-ilb[h][r]));
        vt[m*72 + key]        = bf16_bits((a0[r] + b0) * (1.f + s0));
        vt[(16 + m)*72 + key] = bf16_bits((a1[r] + b1) * (1.f + s1));
      }
    }
    // global token = 65th key (raw gt, not normed/modulated)
    if (t < DHD) ks[64*40 + t] = bf16_bits(gt[b*CC + h*DHD + t]);
    __syncthreads();   // BAR3: proj slice staged; ks/vt/gt-key visible
    // ========== phase attn: stage Q_{h+1} first, then QK/softmax/PV/proj ==
    if (h < NHD - 1) {
#pragma unroll
      for (int u = 0; u < 3; ++u) {
        int ii = rtile * 3 + u;
        stage1k(wf + 2 * (h + 1) * 3072 + ii * 512, wgt[0] + ii * 512, lane);
      }
    }
    short8 qa = *(const short8*)(qs + (rtile*16 + m)*40 + quad*8);
    f32x4 sc[5];
#pragma unroll
    for (int ct = 0; ct < 4; ++ct) {
      short8 kb = *(const short8*)(ks + (ct*16 + m)*40 + quad*8);
      f32x4 z = {0.f,0.f,0.f,0.f};
      sc[ct] = __builtin_amdgcn_mfma_f32_16x16x32_bf16(qa, kb, z, 0,0,0);
    }
    {
      short8 kb = *(const short8*)(ks + 64*40 + quad*8);  // all lanes: gt row (bcast)
      f32x4 z = {0.f,0.f,0.f,0.f};
      sc[4] = __builtin_amdgcn_mfma_f32_16x16x32_bf16(qa, kb, z, 0,0,0);
    }
    // ---- softmax: scores bounded (|s|<=0.177), no max-sub; denom deferred.
    // sc[4][r] is uniform across m (column-broadcast B operand).
    float p64v[4], invr[4];
#pragma unroll
    for (int r = 0; r < 4; ++r) {
      float e0 = __expf(sc[0][r]), e1 = __expf(sc[1][r]);
      float e2 = __expf(sc[2][r]), e3 = __expf(sc[3][r]);
      float e4 = __expf(sc[4][r]);
      int row = key0 + r;
      ps[row*72 + m]      = bf16_bits(e0);
      ps[row*72 + 16 + m] = bf16_bits(e1);
      ps[row*72 + 32 + m] = bf16_bits(e2);
      ps[row*72 + 48 + m] = bf16_bits(e3);
      float sum = row_sum16(e0 + e1 + e2 + e3) + e4;
      invr[r] = __builtin_amdgcn_rcpf(sum);
      p64v[r] = e4;
    }
    // ---- PV (keys 0..63) + rank-1 gt update, normalize at O ----
    f32x4 o0 = {0.f,0.f,0.f,0.f}, o1 = {0.f,0.f,0.f,0.f};
    __builtin_amdgcn_s_setprio(1);
#pragma unroll
    for (int kc = 0; kc < 2; ++kc) {
      short8 pa  = *(const short8*)(ps + (rtile*16 + m)*72 + kc*32 + quad*8);
      short8 vb0 = *(const short8*)(vt + m*72        + kc*32 + quad*8);
      short8 vb1 = *(const short8*)(vt + (16 + m)*72 + kc*32 + quad*8);
      o0 = __builtin_amdgcn_mfma_f32_16x16x32_bf16(pa, vb0, o0, 0,0,0);
      o1 = __builtin_amdgcn_mfma_f32_16x16x32_bf16(pa, vb1, o1, 0,0,0);
    }
    __builtin_amdgcn_s_setprio(0);
    // O_h staged into qs (wave-private rows; qa reads are done above)
#pragma unroll
    for (int r = 0; r < 4; ++r) {
      float pr = p64v[r];
      int row = key0 + r;
      qs[row*40 + m]      = bf16_bits((o0[r] + pr * gv0) * invr[r]);
      qs[row*40 + 16 + m] = bf16_bits((o1[r] + pr * gv1) * invr[r]);
    }
    // ---- accumulate this head's projection slice from B ----
    short8 oa = *(const short8*)(qs + (rtile*16 + m)*40 + quad*8);
    __builtin_amdgcn_s_setprio(1);
#pragma unroll
    for (int ct = 0; ct < 12; ++ct)
      pacc[ct] = __builtin_amdgcn_mfma_f32_16x16x32_bf16(oa, wB8[ct*64 + lane], pacc[ct], 0,0,0);
    __builtin_amdgcn_s_setprio(0);
    __syncthreads();   // BAR4: attn reads done; Q_{h+1} staged
  }
  // ---- epilogue: bias + coalesced store ----
#pragma unroll
  for (int ct = 0; ct < 12; ++ct) {
    float bias = proj_b[ct*16 + m];
#pragma unroll
    for (int r = 0; r < 4; ++r) {
      int row = key0 + r;
      out[base + (size_t)((row >> 3) * WWD + (row & 7)) * CC + ct*16 + m] = pacc[ct][r] + bias;
    }
  }
}

// ------ kernel 5: dwconv -> gelu -> dwconv, += into out (float4-channel) ---
__global__ __launch_bounds__(256) void lcam_pos(const float* __restrict__ x,
                                                const float* __restrict__ w1,
                                                const float* __restrict__ w2,
                                                float* __restrict__ out) {
  __shared__ __align__(16) float xt[20 * 20 * 16];
  __shared__ __align__(16) float t1[18 * 18 * 16];
  __shared__ float wl1[16 * 9], wl2[16 * 9];
  int blk = blockIdx.x;             // b(2) * ty(16) * tx(16) * cg(12)
  int cgI = blk % 12; int tmp = blk / 12;
  int tx = tmp % 16; tmp /= 16;
  int ty = tmp % 16; int b = tmp / 16;
  int c0 = cgI * 16;
  int y0 = ty * 16, x0 = tx * 16;
  int t = threadIdx.x;
  int cc4 = t & 3;                  // invariant float4-channel slot
  if (t < 144) { wl1[t] = w1[c0 * 9 + t]; wl2[t] = w2[c0 * 9 + t]; }
  // stage x halo 20x20x16 (zero outside image = SAME zero pad)
  for (int vi = t; vi < 1600; vi += 256) {
    int q4 = vi & 3;
    int lin = vi >> 2;
    int xx = lin % 20, yy = lin / 20;
    int gy = y0 - 2 + yy, gx = x0 - 2 + xx;
    float4 v = {0.f, 0.f, 0.f, 0.f};
    if (gy >= 0 && gy < HH && gx >= 0 && gx < WWD)
      v = *(const float4*)(x + (((size_t)b * HH + gy) * WWD + gx) * CC + c0 + q4 * 4);
    *(float4*)(xt + (yy * 20 + xx) * 16 + q4 * 4) = v;
  }
  __syncthreads();
  // hoist this thread's 4-channel weight taps into registers
  float w1r[4][9], w2r[4][9];
#pragma unroll
  for (int j = 0; j < 4; ++j)
#pragma unroll
    for (int k = 0; k < 9; ++k) {
      w1r[j][k] = wl1[(cc4 * 4 + j) * 9 + k];
      w2r[j][k] = wl2[(cc4 * 4 + j) * 9 + k];
    }
  // conv1 + exact gelu -> t1 halo 18x18x16 (float4); 0 outside image
  for (int idx = t; idx < 1296; idx += 256) {
    int lin = idx >> 2;
    int xx = lin % 18, yy = lin / 18;
    int gy = y0 - 1 + yy, gx = x0 - 1 + xx;
    float4 r = {0.f, 0.f, 0.f, 0.f};
    if (gy >= 0 && gy < HH && gx >= 0 && gx < WWD) {
#pragma unroll
      for (int ky = 0; ky < 3; ++ky)
#pragma unroll
        for (int kx = 0; kx < 3; ++kx) {
          float4 v = *(const float4*)(xt + ((yy + ky) * 20 + xx + kx) * 16 + cc4 * 4);
          int k = ky * 3 + kx;
          r.x += v.x * w1r[0][k];
          r.y += v.y * w1r[1][k];
          r.z += v.z * w1r[2][k];
          r.w += v.w * w1r[3][k];
        }
      r.x = 0.5f * r.x * (1.f + erff(r.x * 0.70710678118654752f));
      r.y = 0.5f * r.y * (1.f + erff(r.y * 0.70710678118654752f));
      r.z = 0.5f * r.z * (1.f + erff(r.z * 0.70710678118654752f));
      r.w = 0.5f * r.w * (1.f + erff(r.w * 0.70710678118654752f));
    }
    *(float4*)(t1 + (yy * 18 + xx) * 16 + cc4 * 4) = r;
  }
  __syncthreads();
  // conv2 + add into out (float4 RMW, coalesced dwordx4)
  for (int idx = t; idx < 1024; idx += 256) {
    int lin = idx >> 2;
    int xx = lin & 15, yy = lin >> 4;
    float4 r = {0.f, 0.f, 0.f, 0.f};
#pragma unroll
    for (int ky = 0; ky < 3; ++ky)
#pragma unroll
      for (int kx = 0; kx < 3; ++kx) {
        float4 v = *(const float4*)(t1 + ((yy + ky) * 18 + xx + kx) * 16 + cc4 * 4);
        int k = ky * 3 + kx;
        r.x += v.x * w2r[0][k];
        r.y += v.y * w2r[1][k];
        r.z += v.z * w2r[2][k];
        r.w += v.w * w2r[3][k];
      }
    size_t o = (((size_t)b * HH + y0 + yy) * WWD + x0 + xx) * CC + c0 + cc4 * 4;
    float4 cur = *(float4*)(out + o);
    cur.x += r.x; cur.y += r.y; cur.z += r.z; cur.w += r.w;
    *(float4*)(out + o) = cur;
  }
}

extern "C" void kernel_launch(void* const* d_in, const int* in_sizes, int n_in,
                              void* d_out, int out_size, void* d_ws, size_t ws_size,
                              hipStream_t stream) {
  const float* x       = (const float*)d_in[0];
  const float* illu    = (const float*)d_in[1];
  const float* gt_w    = (const float*)d_in[2];
  const float* gt_b    = (const float*)d_in[3];
  const float* qkv_w   = (const float*)d_in[4];
  const float* qkv_b   = (const float*)d_in[5];
  const float* proj_w  = (const float*)d_in[6];
  const float* proj_b  = (const float*)d_in[7];
  const float* conv1_w = (const float*)d_in[8];
  const float* conv2_w = (const float*)d_in[9];
  float* out = (float*)d_out;

  short* wf   = (short*)d_ws;                          // 36*6*64*8 bf16 = 221184 B
  short* pwf  = (short*)((char*)d_ws + 221184);        // 12*6*64*8 bf16 =  73728 B (head-major)
  float* sums = (float*)((char*)d_ws + 221184 + 73728);
  float* gt   = sums + BB * CC;

  hipMemsetAsync(sums, 0, BB * CC * sizeof(float), stream);
  lcam_wshuf2<<<72, 256, 0, stream>>>(qkv_w, proj_w, wf, pwf);
  lcam_sum_x<<<1024, 192, 0, stream>>>(x, sums);
  lcam_gt<<<BB, CC, 0, stream>>>(sums, gt_w, gt_b, gt);
  lcam_attn<<<2048, 256, 0, stream>>>(x, illu, wf, pwf, qkv_b, proj_b, gt, out);
  lcam_pos<<<6144, 256, 0, stream>>>(x, conv1_w, conv2_w, out);
}